// Round 1
// baseline (281.191 us; speedup 1.0000x reference)
//
#include <hip/hip_runtime.h>
#include <math.h>

#define BB 8
#define LL 4096
#define HH 1024
#define SS 32
#define SEPID 102
#define NROWS 256   // B*S
#define TOK 64

// ---------------------------------------------------------------------------
// Kernel 1: per-batch prep — find SEP positions (sorted), build per-token
// segment codes (r = #seps strictly before t, plus is_sep flag), and counts.
// ---------------------------------------------------------------------------
__global__ __launch_bounds__(256) void prep_kernel(
    const int* __restrict__ ids, const int* __restrict__ mask,
    float* __restrict__ cnts, unsigned char* __restrict__ segcode) {
  int b = blockIdx.x;
  int tid = threadIdx.x;
  __shared__ int spos_raw[SS];
  __shared__ int spos[SS];
  __shared__ int scnt[SS];
  __shared__ int nsep;
  if (tid == 0) nsep = 0;
  if (tid < SS) { scnt[tid] = 0; spos_raw[tid] = LL - 1; }
  __syncthreads();
  const int* idb = ids + (size_t)b * LL;
  const int* mb  = mask + (size_t)b * LL;
  for (int t = tid; t < LL; t += blockDim.x) {
    if (idb[t] == SEPID) {
      int slot = atomicAdd(&nsep, 1);
      if (slot < SS) spos_raw[slot] = t;
    }
  }
  __syncthreads();
  // sort the 32 positions by rank (positions are distinct; ties only from fill)
  if (tid < SS) {
    int p = spos_raw[tid];
    int rank = 0;
    for (int j = 0; j < SS; j++) {
      int q = spos_raw[j];
      rank += (q < p) || (q == p && j < tid);
    }
    spos[rank] = p;
  }
  __syncthreads();
  for (int t = tid; t < LL; t += blockDim.x) {
    int r = 0;
#pragma unroll
    for (int j = 0; j < SS; j++) r += (spos[j] < t) ? 1 : 0;
    int issep = (idb[t] == SEPID) ? 1 : 0;
    segcode[(size_t)b * LL + t] = (unsigned char)((r << 1) | issep);
    if (mb[t]) {
      if (issep) {
        atomicAdd(&scnt[r], 1);                 // sep token is ed of seg r
        if (r + 1 < SS) atomicAdd(&scnt[r + 1], 1);  // and st of seg r+1
      } else if (r < SS) {
        atomicAdd(&scnt[r], 1);
      }
    }
  }
  __syncthreads();
  if (tid < SS) cnts[b * SS + tid] = (float)max(scnt[tid], 1);
}

// ---------------------------------------------------------------------------
// Kernel 2: segment sums. Block = 64-token chunk of one batch; thread owns 4
// contiguous H columns (float4). Run-accumulate in registers, flush to global
// sums[b][s][h] with atomicAdd only at segment transitions.
// ---------------------------------------------------------------------------
__device__ __forceinline__ void flush_seg(float* __restrict__ sums, int b,
                                          int seg, int tid, const float4& acc) {
  if (seg >= 0) {
    float* p = sums + ((size_t)(b * SS + seg)) * HH + tid * 4;
    atomicAdd(p + 0, acc.x);
    atomicAdd(p + 1, acc.y);
    atomicAdd(p + 2, acc.z);
    atomicAdd(p + 3, acc.w);
  }
}

__global__ __launch_bounds__(256) void segsum_kernel(
    const float4* __restrict__ seq, const int* __restrict__ mask,
    const unsigned char* __restrict__ segcode, float* __restrict__ sums) {
  const int chunks = LL / TOK;  // 64
  int b = blockIdx.x / chunks;
  int c = blockIdx.x % chunks;
  int t0 = c * TOK;
  int tid = threadIdx.x;  // 0..255 -> h4 column group
  __shared__ int scode[TOK];
  if (tid < TOK) {
    int t = t0 + tid;
    int cd = segcode[(size_t)b * LL + t];
    int m = mask[(size_t)b * LL + t];
    int r = cd >> 1, issep = cd & 1;
    int live = (issep || r < SS) ? 1 : 0;
    scode[tid] = cd | ((m && live) ? 0x100 : 0);  // bit8: token contributes
  }
  __syncthreads();
  float4 acc = make_float4(0.f, 0.f, 0.f, 0.f);
  int curseg = -1;
  const float4* rowbase = seq + (size_t)(b * LL + t0) * (HH / 4) + tid;
  for (int i = 0; i < TOK; i++) {
    float4 v = rowbase[(size_t)i * (HH / 4)];  // unconditional stream
    int cd = scode[i];
    int r = (cd >> 1) & 0x3F;
    int issep = cd & 1;
    float mf = (cd & 0x100) ? 1.f : 0.f;
    v.x *= mf; v.y *= mf; v.z *= mf; v.w *= mf;
    if (issep) {
      if (curseg != r) {
        flush_seg(sums, b, curseg, tid, acc);
        acc = make_float4(0.f, 0.f, 0.f, 0.f);
      }
      acc.x += v.x; acc.y += v.y; acc.z += v.z; acc.w += v.w;
      flush_seg(sums, b, r, tid, acc);  // close segment r
      if (r + 1 < SS) { curseg = r + 1; acc = v; }  // sep also opens seg r+1
      else { curseg = -1; acc = make_float4(0.f, 0.f, 0.f, 0.f); }
    } else {
      int sg = (r < SS) ? r : -1;
      if (sg != curseg) {
        flush_seg(sums, b, curseg, tid, acc);
        curseg = sg;
        acc = make_float4(0.f, 0.f, 0.f, 0.f);
      }
      // v is already zeroed when dead/masked, so unconditional add is safe
      acc.x += v.x; acc.y += v.y; acc.z += v.z; acc.w += v.w;
    }
  }
  flush_seg(sums, b, curseg, tid, acc);
}

// ---------------------------------------------------------------------------
// Kernel 3: h1 = (sums/cnt) @ W1 + b1.  M=256, N=1024, K=1024, fp32 vector.
// 32x32 tiles, K-chunk 32, 2x2 register microtile, 256 threads.
// ---------------------------------------------------------------------------
__global__ __launch_bounds__(256) void gemm1_kernel(
    const float* __restrict__ sums, const float* __restrict__ cnts,
    const float* __restrict__ W1, const float* __restrict__ b1,
    float* __restrict__ h1) {
  __shared__ float As[32][33];
  __shared__ float Bs[32][33];
  __shared__ float inv[32];
  int bj = blockIdx.x;  // col tile 0..31
  int bi = blockIdx.y;  // row tile 0..7
  int tid = threadIdx.x;
  int r0 = bi * 32, c0 = bj * 32;
  if (tid < 32) inv[tid] = 1.0f / cnts[r0 + tid];
  __syncthreads();
  int tx = tid & 15, ty = tid >> 4;
  int la_k = tid & 31;   // k-within-chunk (A) / col (B)
  int la_i = tid >> 5;   // 0..7
  float acc00 = 0.f, acc01 = 0.f, acc10 = 0.f, acc11 = 0.f;
  for (int k0 = 0; k0 < HH; k0 += 32) {
#pragma unroll
    for (int p = 0; p < 4; p++) {
      int i = la_i + p * 8;
      As[i][la_k] = sums[(size_t)(r0 + i) * HH + k0 + la_k] * inv[i];
      Bs[i][la_k] = W1[(size_t)(k0 + i) * HH + c0 + la_k];
    }
    __syncthreads();
#pragma unroll
    for (int kk = 0; kk < 32; kk++) {
      float a0 = As[ty * 2][kk];
      float a1 = As[ty * 2 + 1][kk];
      float b0 = Bs[kk][tx * 2];
      float b1v = Bs[kk][tx * 2 + 1];
      acc00 += a0 * b0; acc01 += a0 * b1v;
      acc10 += a1 * b0; acc11 += a1 * b1v;
    }
    __syncthreads();
  }
  int r = r0 + ty * 2, cc = c0 + tx * 2;
  h1[(size_t)r * HH + cc]           = acc00 + b1[cc];
  h1[(size_t)r * HH + cc + 1]       = acc01 + b1[cc + 1];
  h1[(size_t)(r + 1) * HH + cc]     = acc10 + b1[cc];
  h1[(size_t)(r + 1) * HH + cc + 1] = acc11 + b1[cc + 1];
}

// ---------------------------------------------------------------------------
// Kernel 4: LayerNorm + exact GELU + @W2 + b2. One block per row.
// ---------------------------------------------------------------------------
__global__ __launch_bounds__(256) void final_kernel(
    const float* __restrict__ h1, const float* __restrict__ ln_g,
    const float* __restrict__ ln_b, const float* __restrict__ W2,
    const float* __restrict__ b2, float* __restrict__ out) {
  int r = blockIdx.x;
  int tid = threadIdx.x;
  const float4* x4 = (const float4*)(h1 + (size_t)r * HH);
  float4 x = x4[tid];
  float s = x.x + x.y + x.z + x.w;
  float sq = x.x * x.x + x.y * x.y + x.z * x.z + x.w * x.w;
  __shared__ float redA[4], redB[4];
#pragma unroll
  for (int off = 32; off >= 1; off >>= 1) {
    s += __shfl_down(s, off, 64);
    sq += __shfl_down(sq, off, 64);
  }
  int wave = tid >> 6, lane = tid & 63;
  if (lane == 0) { redA[wave] = s; redB[wave] = sq; }
  __syncthreads();
  float ts = redA[0] + redA[1] + redA[2] + redA[3];
  float tq = redB[0] + redB[1] + redB[2] + redB[3];
  float mean = ts * (1.0f / HH);
  float var = tq * (1.0f / HH) - mean * mean;
  float rinv = rsqrtf(var + 1e-5f);
  float4 g4 = ((const float4*)ln_g)[tid];
  float4 bb4 = ((const float4*)ln_b)[tid];
  float xs[4] = {x.x, x.y, x.z, x.w};
  float gs[4] = {g4.x, g4.y, g4.z, g4.w};
  float bs[4] = {bb4.x, bb4.y, bb4.z, bb4.w};
  float o0 = 0.f, o1 = 0.f;
  int h = tid * 4;
#pragma unroll
  for (int j = 0; j < 4; j++) {
    float y = (xs[j] - mean) * rinv * gs[j] + bs[j];
    float gel = 0.5f * y * (1.0f + erff(y * 0.70710678118654752440f));
    o0 += gel * W2[(size_t)(h + j) * 2 + 0];
    o1 += gel * W2[(size_t)(h + j) * 2 + 1];
  }
#pragma unroll
  for (int off = 32; off >= 1; off >>= 1) {
    o0 += __shfl_down(o0, off, 64);
    o1 += __shfl_down(o1, off, 64);
  }
  __syncthreads();  // done reading redA/redB for LN before reuse
  if (lane == 0) { redA[wave] = o0; redB[wave] = o1; }
  __syncthreads();
  if (tid == 0) {
    float r0 = redA[0] + redA[1] + redA[2] + redA[3] + b2[0];
    float r1 = redB[0] + redB[1] + redB[2] + redB[3] + b2[1];
    out[(size_t)r * 2 + 0] = r0;
    out[(size_t)r * 2 + 1] = r1;
  }
}

// ---------------------------------------------------------------------------
extern "C" void kernel_launch(void* const* d_in, const int* in_sizes, int n_in,
                              void* d_out, int out_size, void* d_ws, size_t ws_size,
                              hipStream_t stream) {
  (void)in_sizes; (void)n_in; (void)out_size; (void)ws_size;
  const float* seq  = (const float*)d_in[0];
  const int*   ids  = (const int*)d_in[1];
  const int*   mask = (const int*)d_in[2];
  const float* W1   = (const float*)d_in[3];
  const float* b1   = (const float*)d_in[4];
  const float* ln_g = (const float*)d_in[5];
  const float* ln_b = (const float*)d_in[6];
  const float* W2   = (const float*)d_in[7];
  const float* b2   = (const float*)d_in[8];
  float* out = (float*)d_out;

  char* ws = (char*)d_ws;
  float* sums = (float*)ws;                               // 1 MB (256*1024 fp32)
  float* h1   = (float*)(ws + (1 << 20));                 // 1 MB
  float* cnts = (float*)(ws + (2 << 20));                 // 1 KB
  unsigned char* segcode = (unsigned char*)(ws + (2 << 20) + 4096);  // 32 KB

  hipMemsetAsync(sums, 0, (size_t)NROWS * HH * sizeof(float), stream);
  prep_kernel<<<BB, 256, 0, stream>>>(ids, mask, cnts, segcode);
  segsum_kernel<<<BB * (LL / TOK), 256, 0, stream>>>(
      (const float4*)seq, mask, segcode, sums);
  dim3 g1(32, 8);
  gemm1_kernel<<<g1, 256, 0, stream>>>(sums, cnts, W1, b1, h1);
  final_kernel<<<NROWS, 256, 0, stream>>>(h1, ln_g, ln_b, W2, b2, out);
}

// Round 2
// 262.140 us; speedup vs baseline: 1.0727x; 1.0727x over previous
//
#include <hip/hip_runtime.h>
#include <math.h>

#define BB 8
#define LL 4096
#define HH 1024
#define SS 32
#define SEPID 102
#define NROWS 256   // B*S
#define TOK 64

// ---------------------------------------------------------------------------
// Kernel 1: per-batch prep. Finds SEP positions (sorted), computes per-segment
// masked counts via block scan (no LDS atomics), and per-token segment codes
// via binary search (5 LDS broadcast reads instead of 32 compares).
// ---------------------------------------------------------------------------
__global__ __launch_bounds__(256) void prep_kernel(
    const int* __restrict__ ids, const int* __restrict__ mask,
    float* __restrict__ cnts, unsigned char* __restrict__ segcode) {
  int b = blockIdx.x;
  int tid = threadIdx.x;
  __shared__ int spos_raw[SS];
  __shared__ int spos[SS];
  __shared__ int nsep;
  __shared__ int excl_s[257];   // exclusive prefix of 16-token chunk sums
  __shared__ int wtot[4];
  if (tid == 0) nsep = 0;
  if (tid < SS) spos_raw[tid] = LL - 1;
  __syncthreads();
  const int* idb = ids + (size_t)b * LL;
  const int* mb  = mask + (size_t)b * LL;

  // --- find SEP positions (unordered) ---
  for (int t = tid; t < LL; t += 256) {
    if (idb[t] == SEPID) {
      int slot = atomicAdd(&nsep, 1);
      if (slot < SS) spos_raw[slot] = t;
    }
  }
  __syncthreads();
  // --- sort 32 positions by rank ---
  if (tid < SS) {
    int p = spos_raw[tid];
    int rank = 0;
    for (int j = 0; j < SS; j++) {
      int q = spos_raw[j];
      rank += (q < p) || (q == p && j < tid);
    }
    spos[rank] = p;
  }

  // --- block scan of mask in 16-token chunks ---
  int local = 0;
  int base = tid * 16;
#pragma unroll
  for (int i = 0; i < 16; i++) local += mb[base + i];
  int lane = tid & 63, wave = tid >> 6;
  int v = local;
#pragma unroll
  for (int off = 1; off < 64; off <<= 1) {
    int n = __shfl_up(v, off, 64);
    if (lane >= off) v += n;
  }
  if (lane == 63) wtot[wave] = v;
  __syncthreads();
  int woff = 0;
  for (int w = 0; w < wave; w++) woff += wtot[w];
  excl_s[tid] = woff + v - local;   // exclusive prefix of chunk tid
  if (tid == 0) excl_s[256] = wtot[0] + wtot[1] + wtot[2] + wtot[3];
  __syncthreads();

  // --- per-segment masked counts: cnt[s] = C[ed+1] - C[st] ---
  if (tid < SS) {
    int st = (tid == 0) ? 0 : spos[tid - 1];
    int ed = spos[tid];
    int pa = st, pb = ed + 1;
    int ca = excl_s[pa >> 4];
    for (int i = pa & ~15; i < pa; i++) ca += mb[i];
    int cb = excl_s[pb >> 4];
    for (int i = pb & ~15; i < pb; i++) cb += mb[i];
    cnts[b * SS + tid] = (float)max(cb - ca, 1);
  }

  // --- per-token segment code: r = #{spos[j] < t} via binary search ---
  for (int t = tid; t < LL; t += 256) {
    int lo = 0, hi = SS;
    while (lo < hi) {
      int mid = (lo + hi) >> 1;
      lo = (spos[mid] < t) ? mid + 1 : lo;
      hi = (spos[mid] < t) ? hi : mid;
    }
    int issep = (idb[t] == SEPID) ? 1 : 0;
    segcode[(size_t)b * LL + t] = (unsigned char)((lo << 1) | issep);
  }
}

// ---------------------------------------------------------------------------
// Kernel 2: segment sums. Block = 64-token chunk; thread owns 4 H columns
// (float4). Run-accumulate in registers, atomic flush at segment transitions.
// ---------------------------------------------------------------------------
__device__ __forceinline__ void flush_seg(float* __restrict__ sums, int b,
                                          int seg, int tid, const float4& acc) {
  if (seg >= 0) {
    float* p = sums + ((size_t)(b * SS + seg)) * HH + tid * 4;
    atomicAdd(p + 0, acc.x);
    atomicAdd(p + 1, acc.y);
    atomicAdd(p + 2, acc.z);
    atomicAdd(p + 3, acc.w);
  }
}

__global__ __launch_bounds__(256) void segsum_kernel(
    const float4* __restrict__ seq, const int* __restrict__ mask,
    const unsigned char* __restrict__ segcode, float* __restrict__ sums) {
  const int chunks = LL / TOK;  // 64
  int b = blockIdx.x / chunks;
  int c = blockIdx.x % chunks;
  int t0 = c * TOK;
  int tid = threadIdx.x;
  __shared__ int scode[TOK];
  if (tid < TOK) {
    int t = t0 + tid;
    int cd = segcode[(size_t)b * LL + t];
    int m = mask[(size_t)b * LL + t];
    int r = cd >> 1, issep = cd & 1;
    int live = (issep || r < SS) ? 1 : 0;
    scode[tid] = cd | ((m && live) ? 0x100 : 0);
  }
  __syncthreads();
  float4 acc = make_float4(0.f, 0.f, 0.f, 0.f);
  int curseg = -1;
  const float4* rowbase = seq + (size_t)(b * LL + t0) * (HH / 4) + tid;
  for (int i = 0; i < TOK; i++) {
    float4 v = rowbase[(size_t)i * (HH / 4)];
    int cd = scode[i];
    int r = (cd >> 1) & 0x3F;
    int issep = cd & 1;
    float mf = (cd & 0x100) ? 1.f : 0.f;
    v.x *= mf; v.y *= mf; v.z *= mf; v.w *= mf;
    if (issep) {
      if (curseg != r) {
        flush_seg(sums, b, curseg, tid, acc);
        acc = make_float4(0.f, 0.f, 0.f, 0.f);
      }
      acc.x += v.x; acc.y += v.y; acc.z += v.z; acc.w += v.w;
      flush_seg(sums, b, r, tid, acc);
      if (r + 1 < SS) { curseg = r + 1; acc = v; }
      else { curseg = -1; acc = make_float4(0.f, 0.f, 0.f, 0.f); }
    } else {
      int sg = (r < SS) ? r : -1;
      if (sg != curseg) {
        flush_seg(sums, b, curseg, tid, acc);
        curseg = sg;
        acc = make_float4(0.f, 0.f, 0.f, 0.f);
      }
      acc.x += v.x; acc.y += v.y; acc.z += v.z; acc.w += v.w;
    }
  }
  flush_seg(sums, b, curseg, tid, acc);
}

// ---------------------------------------------------------------------------
// Kernel 3: h1 += (sums/cnt) @ W1, split-K x4 (atomicAdd into zeroed h1).
// Grid (32 col-tiles, 8 row-tiles, 4 K-slices), 256 thr, 32x32 tile, 2x2 micro.
// ---------------------------------------------------------------------------
__global__ __launch_bounds__(256) void gemm1_kernel(
    const float* __restrict__ sums, const float* __restrict__ cnts,
    const float* __restrict__ W1, float* __restrict__ h1) {
  __shared__ float As[32][33];
  __shared__ float Bs[32][33];
  __shared__ float inv[32];
  int bj = blockIdx.x;   // col tile 0..31
  int bi = blockIdx.y;   // row tile 0..7
  int bz = blockIdx.z;   // K slice 0..3
  int tid = threadIdx.x;
  int r0 = bi * 32, c0 = bj * 32, kb = bz * 256;
  if (tid < 32) inv[tid] = 1.0f / cnts[r0 + tid];
  __syncthreads();
  int tx = tid & 15, ty = tid >> 4;
  int la_k = tid & 31;
  int la_i = tid >> 5;
  float acc00 = 0.f, acc01 = 0.f, acc10 = 0.f, acc11 = 0.f;
  for (int k0 = kb; k0 < kb + 256; k0 += 32) {
#pragma unroll
    for (int p = 0; p < 4; p++) {
      int i = la_i + p * 8;
      As[i][la_k] = sums[(size_t)(r0 + i) * HH + k0 + la_k] * inv[i];
      Bs[i][la_k] = W1[(size_t)(k0 + i) * HH + c0 + la_k];
    }
    __syncthreads();
#pragma unroll
    for (int kk = 0; kk < 32; kk++) {
      float a0 = As[ty * 2][kk];
      float a1 = As[ty * 2 + 1][kk];
      float b0 = Bs[kk][tx * 2];
      float b1v = Bs[kk][tx * 2 + 1];
      acc00 += a0 * b0; acc01 += a0 * b1v;
      acc10 += a1 * b0; acc11 += a1 * b1v;
    }
    __syncthreads();
  }
  int r = r0 + ty * 2, cc = c0 + tx * 2;
  atomicAdd(&h1[(size_t)r * HH + cc], acc00);
  atomicAdd(&h1[(size_t)r * HH + cc + 1], acc01);
  atomicAdd(&h1[(size_t)(r + 1) * HH + cc], acc10);
  atomicAdd(&h1[(size_t)(r + 1) * HH + cc + 1], acc11);
}

// ---------------------------------------------------------------------------
// Kernel 4: (h1 + b1) -> LayerNorm -> exact GELU -> @W2 + b2. Block per row.
// ---------------------------------------------------------------------------
__global__ __launch_bounds__(256) void final_kernel(
    const float* __restrict__ h1, const float* __restrict__ b1,
    const float* __restrict__ ln_g, const float* __restrict__ ln_b,
    const float* __restrict__ W2, const float* __restrict__ b2,
    float* __restrict__ out) {
  int r = blockIdx.x;
  int tid = threadIdx.x;
  float4 x = ((const float4*)(h1 + (size_t)r * HH))[tid];
  float4 bb1 = ((const float4*)b1)[tid];
  x.x += bb1.x; x.y += bb1.y; x.z += bb1.z; x.w += bb1.w;
  float s = x.x + x.y + x.z + x.w;
  float sq = x.x * x.x + x.y * x.y + x.z * x.z + x.w * x.w;
  __shared__ float redA[4], redB[4];
#pragma unroll
  for (int off = 32; off >= 1; off >>= 1) {
    s += __shfl_down(s, off, 64);
    sq += __shfl_down(sq, off, 64);
  }
  int wave = tid >> 6, lane = tid & 63;
  if (lane == 0) { redA[wave] = s; redB[wave] = sq; }
  __syncthreads();
  float ts = redA[0] + redA[1] + redA[2] + redA[3];
  float tq = redB[0] + redB[1] + redB[2] + redB[3];
  float mean = ts * (1.0f / HH);
  float var = tq * (1.0f / HH) - mean * mean;
  float rinv = rsqrtf(var + 1e-5f);
  float4 g4 = ((const float4*)ln_g)[tid];
  float4 bb4 = ((const float4*)ln_b)[tid];
  float4 w20 = ((const float4*)W2)[tid * 2];       // W2[h..h+1][0..1]
  float4 w21 = ((const float4*)W2)[tid * 2 + 1];   // W2[h+2..h+3][0..1]
  float xs[4] = {x.x, x.y, x.z, x.w};
  float gs[4] = {g4.x, g4.y, g4.z, g4.w};
  float bs[4] = {bb4.x, bb4.y, bb4.z, bb4.w};
  float w0[4] = {w20.x, w20.z, w21.x, w21.z};
  float w1[4] = {w20.y, w20.w, w21.y, w21.w};
  float o0 = 0.f, o1 = 0.f;
#pragma unroll
  for (int j = 0; j < 4; j++) {
    float y = (xs[j] - mean) * rinv * gs[j] + bs[j];
    float gel = 0.5f * y * (1.0f + erff(y * 0.70710678118654752440f));
    o0 += gel * w0[j];
    o1 += gel * w1[j];
  }
#pragma unroll
  for (int off = 32; off >= 1; off >>= 1) {
    o0 += __shfl_down(o0, off, 64);
    o1 += __shfl_down(o1, off, 64);
  }
  __syncthreads();
  if (lane == 0) { redA[wave] = o0; redB[wave] = o1; }
  __syncthreads();
  if (tid == 0) {
    out[(size_t)r * 2 + 0] = redA[0] + redA[1] + redA[2] + redA[3] + b2[0];
    out[(size_t)r * 2 + 1] = redB[0] + redB[1] + redB[2] + redB[3] + b2[1];
  }
}

// ---------------------------------------------------------------------------
extern "C" void kernel_launch(void* const* d_in, const int* in_sizes, int n_in,
                              void* d_out, int out_size, void* d_ws, size_t ws_size,
                              hipStream_t stream) {
  (void)in_sizes; (void)n_in; (void)out_size; (void)ws_size;
  const float* seq  = (const float*)d_in[0];
  const int*   ids  = (const int*)d_in[1];
  const int*   mask = (const int*)d_in[2];
  const float* W1   = (const float*)d_in[3];
  const float* b1   = (const float*)d_in[4];
  const float* ln_g = (const float*)d_in[5];
  const float* ln_b = (const float*)d_in[6];
  const float* W2   = (const float*)d_in[7];
  const float* b2   = (const float*)d_in[8];
  float* out = (float*)d_out;

  char* ws = (char*)d_ws;
  float* sums = (float*)ws;                        // 1 MB
  float* h1   = (float*)(ws + (1 << 20));          // 1 MB (adjacent -> one memset)
  float* cnts = (float*)(ws + (2 << 20));          // 1 KB
  unsigned char* segcode = (unsigned char*)(ws + (2 << 20) + 4096);  // 32 KB

  hipMemsetAsync(ws, 0, 2u << 20, stream);         // zero sums + h1 together
  prep_kernel<<<BB, 256, 0, stream>>>(ids, mask, cnts, segcode);
  segsum_kernel<<<BB * (LL / TOK), 256, 0, stream>>>(
      (const float4*)seq, mask, segcode, sums);
  dim3 g1(32, 8, 4);
  gemm1_kernel<<<g1, 256, 0, stream>>>(sums, cnts, W1, h1);
  final_kernel<<<NROWS, 256, 0, stream>>>(h1, b1, ln_g, ln_b, W2, b2, out);
}

// Round 3
// 243.185 us; speedup vs baseline: 1.1563x; 1.0779x over previous
//
#include <hip/hip_runtime.h>
#include <math.h>

#define BB 8
#define LL 4096
#define HH 1024
#define SS 32
#define SEPID 102
#define NROWS 256   // B*S
#define TOK 64
#define SPLITK 8
#define KSLICE (HH / SPLITK)  // 128

// ---------------------------------------------------------------------------
// Kernel 1: per-batch prep. Finds SEP positions (sorted) -> spos_g, computes
// per-segment masked counts via block scan. No per-token pass.
// ---------------------------------------------------------------------------
__global__ __launch_bounds__(256) void prep_kernel(
    const int* __restrict__ ids, const int* __restrict__ mask,
    float* __restrict__ cnts, int* __restrict__ spos_g) {
  int b = blockIdx.x;
  int tid = threadIdx.x;
  __shared__ int spos_raw[SS];
  __shared__ int spos[SS];
  __shared__ int nsep;
  __shared__ int excl_s[257];
  __shared__ int wtot[4];
  if (tid == 0) nsep = 0;
  if (tid < SS) spos_raw[tid] = LL - 1;
  __syncthreads();
  const int* idb = ids + (size_t)b * LL;
  const int* mb  = mask + (size_t)b * LL;

  for (int t = tid; t < LL; t += 256) {
    if (idb[t] == SEPID) {
      int slot = atomicAdd(&nsep, 1);
      if (slot < SS) spos_raw[slot] = t;
    }
  }
  __syncthreads();
  if (tid < SS) {
    int p = spos_raw[tid];
    int rank = 0;
    for (int j = 0; j < SS; j++) {
      int q = spos_raw[j];
      rank += (q < p) || (q == p && j < tid);
    }
    spos[rank] = p;
  }

  // block scan of mask in 16-token chunks
  int local = 0;
  int base = tid * 16;
#pragma unroll
  for (int i = 0; i < 16; i++) local += mb[base + i];
  int lane = tid & 63, wave = tid >> 6;
  int v = local;
#pragma unroll
  for (int off = 1; off < 64; off <<= 1) {
    int n = __shfl_up(v, off, 64);
    if (lane >= off) v += n;
  }
  if (lane == 63) wtot[wave] = v;
  __syncthreads();
  int woff = 0;
  for (int w = 0; w < wave; w++) woff += wtot[w];
  excl_s[tid] = woff + v - local;
  if (tid == 0) excl_s[256] = wtot[0] + wtot[1] + wtot[2] + wtot[3];
  __syncthreads();

  if (tid < SS) {
    spos_g[b * SS + tid] = spos[tid];
    int st = (tid == 0) ? 0 : spos[tid - 1];
    int ed = spos[tid];
    int pa = st, pb = ed + 1;
    int ca = excl_s[pa >> 4];
    for (int i = pa & ~15; i < pa; i++) ca += mb[i];
    int cb = excl_s[pb >> 4];
    for (int i = pb & ~15; i < pb; i++) cb += mb[i];
    cnts[b * SS + tid] = (float)max(cb - ca, 1);
  }
}

// ---------------------------------------------------------------------------
// Kernel 2: segment sums. Block = 64-token chunk; segment codes computed
// inline from the 32 sorted SEP positions (binary search, LDS broadcast).
// ---------------------------------------------------------------------------
__device__ __forceinline__ void flush_seg(float* __restrict__ sums, int b,
                                          int seg, int tid, const float4& acc) {
  if (seg >= 0) {
    float* p = sums + ((size_t)(b * SS + seg)) * HH + tid * 4;
    atomicAdd(p + 0, acc.x);
    atomicAdd(p + 1, acc.y);
    atomicAdd(p + 2, acc.z);
    atomicAdd(p + 3, acc.w);
  }
}

__global__ __launch_bounds__(256) void segsum_kernel(
    const float4* __restrict__ seq, const int* __restrict__ mask,
    const int* __restrict__ spos_g, float* __restrict__ sums) {
  const int chunks = LL / TOK;  // 64
  int b = blockIdx.x / chunks;
  int c = blockIdx.x % chunks;
  int t0 = c * TOK;
  int tid = threadIdx.x;
  __shared__ int sposs[SS];
  __shared__ int scode[TOK];
  if (tid < SS) sposs[tid] = spos_g[b * SS + tid];
  __syncthreads();
  if (tid < TOK) {
    int t = t0 + tid;
    int lo = 0, hi = SS;
    while (lo < hi) {
      int mid = (lo + hi) >> 1;
      if (sposs[mid] < t) lo = mid + 1; else hi = mid;
    }
    int issep = (lo < SS && sposs[lo] == t) ? 1 : 0;
    int r = lo;
    int m = mask[(size_t)b * LL + t];
    int live = (issep || r < SS) ? 1 : 0;
    scode[tid] = ((r << 1) | issep) | ((m && live) ? 0x100 : 0);
  }
  __syncthreads();
  float4 acc = make_float4(0.f, 0.f, 0.f, 0.f);
  int curseg = -1;
  const float4* rowbase = seq + (size_t)(b * LL + t0) * (HH / 4) + tid;
  for (int i = 0; i < TOK; i++) {
    float4 v = rowbase[(size_t)i * (HH / 4)];
    int cd = scode[i];
    int r = (cd >> 1) & 0x3F;
    int issep = cd & 1;
    float mf = (cd & 0x100) ? 1.f : 0.f;
    v.x *= mf; v.y *= mf; v.z *= mf; v.w *= mf;
    if (issep) {
      if (curseg != r) {
        flush_seg(sums, b, curseg, tid, acc);
        acc = make_float4(0.f, 0.f, 0.f, 0.f);
      }
      acc.x += v.x; acc.y += v.y; acc.z += v.z; acc.w += v.w;
      flush_seg(sums, b, r, tid, acc);
      if (r + 1 < SS) { curseg = r + 1; acc = v; }
      else { curseg = -1; acc = make_float4(0.f, 0.f, 0.f, 0.f); }
    } else {
      int sg = (r < SS) ? r : -1;
      if (sg != curseg) {
        flush_seg(sums, b, curseg, tid, acc);
        curseg = sg;
        acc = make_float4(0.f, 0.f, 0.f, 0.f);
      }
      acc.x += v.x; acc.y += v.y; acc.z += v.z; acc.w += v.w;
    }
  }
  flush_seg(sums, b, curseg, tid, acc);
}

// ---------------------------------------------------------------------------
// Kernel 3: split-K GEMM, partials (no atomics). 64x64 tile, 4x4 microtile,
// k-major LDS with b128 reads. h1p[slice][row][col], slice = blockIdx.z.
// ---------------------------------------------------------------------------
__global__ __launch_bounds__(256) void gemm1_kernel(
    const float* __restrict__ sums, const float* __restrict__ cnts,
    const float* __restrict__ W1, float* __restrict__ h1p) {
  __shared__ float As[32][68];   // [kk][row], +4 pad keeps 16B alignment
  __shared__ float Bs[32][68];   // [kk][col]
  __shared__ float inv[64];
  int bj = blockIdx.x;  // 0..15 col tile
  int bi = blockIdx.y;  // 0..3  row tile
  int bz = blockIdx.z;  // 0..7  K slice
  int tid = threadIdx.x;
  int r0 = bi * 64, c0 = bj * 64, kb = bz * KSLICE;
  if (tid < 64) inv[tid] = 1.0f / cnts[r0 + tid];

  int ai = tid >> 3;        // 0..31 (row; also +32)
  int af = tid & 7;         // float4 index along k
  int bk = tid >> 4;        // 0..15 (k row; also +16)
  int bj4 = tid & 15;       // float4 index along n
  int tx = tid & 15, ty = tid >> 4;

  float acc[4][4];
#pragma unroll
  for (int i = 0; i < 4; i++)
#pragma unroll
    for (int j = 0; j < 4; j++) acc[i][j] = 0.f;

  for (int k0 = kb; k0 < kb + KSLICE; k0 += 32) {
    __syncthreads();  // also covers inv on first iteration
    float4 a0 = *(const float4*)&sums[(size_t)(r0 + ai) * HH + k0 + af * 4];
    float4 a1 = *(const float4*)&sums[(size_t)(r0 + ai + 32) * HH + k0 + af * 4];
    float4 b0 = *(const float4*)&W1[(size_t)(k0 + bk) * HH + c0 + bj4 * 4];
    float4 b1 = *(const float4*)&W1[(size_t)(k0 + bk + 16) * HH + c0 + bj4 * 4];
    float i0 = inv[ai], i1 = inv[ai + 32];
    As[af * 4 + 0][ai] = a0.x * i0;
    As[af * 4 + 1][ai] = a0.y * i0;
    As[af * 4 + 2][ai] = a0.z * i0;
    As[af * 4 + 3][ai] = a0.w * i0;
    As[af * 4 + 0][ai + 32] = a1.x * i1;
    As[af * 4 + 1][ai + 32] = a1.y * i1;
    As[af * 4 + 2][ai + 32] = a1.z * i1;
    As[af * 4 + 3][ai + 32] = a1.w * i1;
    *(float4*)&Bs[bk][bj4 * 4] = b0;
    *(float4*)&Bs[bk + 16][bj4 * 4] = b1;
    __syncthreads();
#pragma unroll
    for (int kk = 0; kk < 32; kk++) {
      float4 a = *(const float4*)&As[kk][ty * 4];
      float4 b = *(const float4*)&Bs[kk][tx * 4];
      acc[0][0] += a.x * b.x; acc[0][1] += a.x * b.y;
      acc[0][2] += a.x * b.z; acc[0][3] += a.x * b.w;
      acc[1][0] += a.y * b.x; acc[1][1] += a.y * b.y;
      acc[1][2] += a.y * b.z; acc[1][3] += a.y * b.w;
      acc[2][0] += a.z * b.x; acc[2][1] += a.z * b.y;
      acc[2][2] += a.z * b.z; acc[2][3] += a.z * b.w;
      acc[3][0] += a.w * b.x; acc[3][1] += a.w * b.y;
      acc[3][2] += a.w * b.z; acc[3][3] += a.w * b.w;
    }
  }
#pragma unroll
  for (int dr = 0; dr < 4; dr++) {
    float4 o = make_float4(acc[dr][0], acc[dr][1], acc[dr][2], acc[dr][3]);
    *(float4*)&h1p[((size_t)bz * NROWS + r0 + ty * 4 + dr) * HH + c0 + tx * 4] = o;
  }
}

// ---------------------------------------------------------------------------
// Kernel 4: sum 8 partials + b1 -> LayerNorm -> exact GELU -> @W2 + b2.
// ---------------------------------------------------------------------------
__global__ __launch_bounds__(256) void final_kernel(
    const float* __restrict__ h1p, const float* __restrict__ b1,
    const float* __restrict__ ln_g, const float* __restrict__ ln_b,
    const float* __restrict__ W2, const float* __restrict__ b2,
    float* __restrict__ out) {
  int r = blockIdx.x;
  int tid = threadIdx.x;
  float4 x = ((const float4*)b1)[tid];
#pragma unroll
  for (int sl = 0; sl < SPLITK; sl++) {
    float4 p = ((const float4*)(h1p + ((size_t)sl * NROWS + r) * HH))[tid];
    x.x += p.x; x.y += p.y; x.z += p.z; x.w += p.w;
  }
  float s = x.x + x.y + x.z + x.w;
  float sq = x.x * x.x + x.y * x.y + x.z * x.z + x.w * x.w;
  __shared__ float redA[4], redB[4];
#pragma unroll
  for (int off = 32; off >= 1; off >>= 1) {
    s += __shfl_down(s, off, 64);
    sq += __shfl_down(sq, off, 64);
  }
  int wave = tid >> 6, lane = tid & 63;
  if (lane == 0) { redA[wave] = s; redB[wave] = sq; }
  __syncthreads();
  float ts = redA[0] + redA[1] + redA[2] + redA[3];
  float tq = redB[0] + redB[1] + redB[2] + redB[3];
  float mean = ts * (1.0f / HH);
  float var = tq * (1.0f / HH) - mean * mean;
  float rinv = rsqrtf(var + 1e-5f);
  float4 g4 = ((const float4*)ln_g)[tid];
  float4 bb4 = ((const float4*)ln_b)[tid];
  float4 w20 = ((const float4*)W2)[tid * 2];
  float4 w21 = ((const float4*)W2)[tid * 2 + 1];
  float xs[4] = {x.x, x.y, x.z, x.w};
  float gs[4] = {g4.x, g4.y, g4.z, g4.w};
  float bs[4] = {bb4.x, bb4.y, bb4.z, bb4.w};
  float w0[4] = {w20.x, w20.z, w21.x, w21.z};
  float w1[4] = {w20.y, w20.w, w21.y, w21.w};
  float o0 = 0.f, o1 = 0.f;
#pragma unroll
  for (int j = 0; j < 4; j++) {
    float y = (xs[j] - mean) * rinv * gs[j] + bs[j];
    float gel = 0.5f * y * (1.0f + erff(y * 0.70710678118654752440f));
    o0 += gel * w0[j];
    o1 += gel * w1[j];
  }
#pragma unroll
  for (int off = 32; off >= 1; off >>= 1) {
    o0 += __shfl_down(o0, off, 64);
    o1 += __shfl_down(o1, off, 64);
  }
  __syncthreads();
  if (lane == 0) { redA[wave] = o0; redB[wave] = o1; }
  __syncthreads();
  if (tid == 0) {
    out[(size_t)r * 2 + 0] = redA[0] + redA[1] + redA[2] + redA[3] + b2[0];
    out[(size_t)r * 2 + 1] = redB[0] + redB[1] + redB[2] + redB[3] + b2[1];
  }
}

// ---------------------------------------------------------------------------
extern "C" void kernel_launch(void* const* d_in, const int* in_sizes, int n_in,
                              void* d_out, int out_size, void* d_ws, size_t ws_size,
                              hipStream_t stream) {
  (void)in_sizes; (void)n_in; (void)out_size; (void)ws_size;
  const float* seq  = (const float*)d_in[0];
  const int*   ids  = (const int*)d_in[1];
  const int*   mask = (const int*)d_in[2];
  const float* W1   = (const float*)d_in[3];
  const float* b1   = (const float*)d_in[4];
  const float* ln_g = (const float*)d_in[5];
  const float* ln_b = (const float*)d_in[6];
  const float* W2   = (const float*)d_in[7];
  const float* b2   = (const float*)d_in[8];
  float* out = (float*)d_out;

  char* ws = (char*)d_ws;
  float* sums = (float*)ws;                         // 1 MB (needs zeroing)
  float* h1p  = (float*)(ws + (1 << 20));           // 8 MB partials
  float* cnts = (float*)(ws + (9 << 20));           // 1 KB
  int*   spos = (int*)(ws + (9 << 20) + 4096);      // 1 KB

  hipMemsetAsync(sums, 0, (size_t)NROWS * HH * sizeof(float), stream);
  prep_kernel<<<BB, 256, 0, stream>>>(ids, mask, cnts, spos);
  segsum_kernel<<<BB * (LL / TOK), 256, 0, stream>>>(
      (const float4*)seq, mask, spos, sums);
  dim3 g1(16, 4, SPLITK);
  gemm1_kernel<<<g1, 256, 0, stream>>>(sums, cnts, W1, h1p);
  final_kernel<<<NROWS, 256, 0, stream>>>(h1p, b1, ln_g, ln_b, W2, b2, out);
}

// Round 4
// 239.889 us; speedup vs baseline: 1.1722x; 1.0137x over previous
//
#include <hip/hip_runtime.h>
#include <math.h>

#define BB 8
#define LL 4096
#define HH 1024
#define SS 32
#define SEPID 102
#define NROWS 256   // B*S
#define TOK 64
#define SPLITK 8
#define KSLICE (HH / SPLITK)  // 128

// ---------------------------------------------------------------------------
// Kernel 1: per-batch prep + sums zeroing.
// blockIdx.y == 0: find SEP positions (sorted) -> spos_g, masked counts via
// block scan -> cnts. blockIdx.y in 1..8: zero a 1/64 slice of sums.
// ---------------------------------------------------------------------------
__global__ __launch_bounds__(256) void prep_kernel(
    const int* __restrict__ ids, const int* __restrict__ mask,
    float* __restrict__ cnts, int* __restrict__ spos_g,
    float* __restrict__ sums) {
  int b = blockIdx.x;
  int by = blockIdx.y;
  int tid = threadIdx.x;
  if (by > 0) {
    // zero slice: 64 zero-blocks x 1024 float4 = 1 MB total
    int z = b * 8 + (by - 1);
    float4 zero = make_float4(0.f, 0.f, 0.f, 0.f);
    float4* p = (float4*)sums + (size_t)z * 1024;
#pragma unroll
    for (int i = 0; i < 4; i++) p[tid + i * 256] = zero;
    return;
  }
  __shared__ int spos_raw[SS];
  __shared__ int spos[SS];
  __shared__ int nsep;
  __shared__ int excl_s[257];
  __shared__ int wtot[4];
  if (tid == 0) nsep = 0;
  if (tid < SS) spos_raw[tid] = LL - 1;
  __syncthreads();
  const int* idb = ids + (size_t)b * LL;
  const int* mb  = mask + (size_t)b * LL;

  for (int t = tid; t < LL; t += 256) {
    if (idb[t] == SEPID) {
      int slot = atomicAdd(&nsep, 1);
      if (slot < SS) spos_raw[slot] = t;
    }
  }
  __syncthreads();
  if (tid < SS) {
    int p = spos_raw[tid];
    int rank = 0;
    for (int j = 0; j < SS; j++) {
      int q = spos_raw[j];
      rank += (q < p) || (q == p && j < tid);
    }
    spos[rank] = p;
  }

  // block scan of mask in 16-token chunks
  int local = 0;
  int base = tid * 16;
#pragma unroll
  for (int i = 0; i < 16; i++) local += mb[base + i];
  int lane = tid & 63, wave = tid >> 6;
  int v = local;
#pragma unroll
  for (int off = 1; off < 64; off <<= 1) {
    int n = __shfl_up(v, off, 64);
    if (lane >= off) v += n;
  }
  if (lane == 63) wtot[wave] = v;
  __syncthreads();
  int woff = 0;
  for (int w = 0; w < wave; w++) woff += wtot[w];
  excl_s[tid] = woff + v - local;
  if (tid == 0) excl_s[256] = wtot[0] + wtot[1] + wtot[2] + wtot[3];
  __syncthreads();

  if (tid < SS) {
    spos_g[b * SS + tid] = spos[tid];
    int st = (tid == 0) ? 0 : spos[tid - 1];
    int ed = spos[tid];
    int pa = st, pb = ed + 1;
    int ca = excl_s[pa >> 4];
    for (int i = pa & ~15; i < pa; i++) ca += mb[i];
    int cb = excl_s[pb >> 4];
    for (int i = pb & ~15; i < pb; i++) cb += mb[i];
    cnts[b * SS + tid] = (float)max(cb - ca, 1);
  }
}

// ---------------------------------------------------------------------------
// Kernel 2: segment sums. Block = 64-token chunk; codes from binary search of
// the 32 sorted SEP positions. Early-exit for all-dead chunks; distance-1
// prefetch keeps a global load in flight past the flush atomics.
// ---------------------------------------------------------------------------
__device__ __forceinline__ void flush_seg(float* __restrict__ sums, int b,
                                          int seg, int tid, const float4& acc) {
  if (seg >= 0) {
    float* p = sums + ((size_t)(b * SS + seg)) * HH + tid * 4;
    atomicAdd(p + 0, acc.x);
    atomicAdd(p + 1, acc.y);
    atomicAdd(p + 2, acc.z);
    atomicAdd(p + 3, acc.w);
  }
}

__global__ __launch_bounds__(256) void segsum_kernel(
    const float4* __restrict__ seq, const int* __restrict__ mask,
    const int* __restrict__ spos_g, float* __restrict__ sums) {
  const int chunks = LL / TOK;  // 64
  int b = blockIdx.x / chunks;
  int c = blockIdx.x % chunks;
  int t0 = c * TOK;
  int tid = threadIdx.x;
  __shared__ int sposs[SS];
  __shared__ int scode[TOK];
  if (tid < SS) sposs[tid] = spos_g[b * SS + tid];
  __syncthreads();
  if (t0 > sposs[SS - 1]) return;  // whole chunk after last SEP: contributes 0
  if (tid < TOK) {
    int t = t0 + tid;
    int lo = 0, hi = SS;
    while (lo < hi) {
      int mid = (lo + hi) >> 1;
      if (sposs[mid] < t) lo = mid + 1; else hi = mid;
    }
    int issep = (lo < SS && sposs[lo] == t) ? 1 : 0;
    int r = lo;
    int m = mask[(size_t)b * LL + t];
    int live = (issep || r < SS) ? 1 : 0;
    scode[tid] = ((r << 1) | issep) | ((m && live) ? 0x100 : 0);
  }
  __syncthreads();
  float4 acc = make_float4(0.f, 0.f, 0.f, 0.f);
  int curseg = -1;
  const int rs = HH / 4;  // row stride in float4
  const float4* rowbase = seq + (size_t)(b * LL + t0) * rs + tid;
  float4 vcur = rowbase[0];
  for (int i = 0; i < TOK; i++) {
    int nx = (i + 1 < TOK) ? (i + 1) : (TOK - 1);
    float4 vnext = rowbase[(size_t)nx * rs];
    int cd = scode[i];
    int r = (cd >> 1) & 0x3F;
    int issep = cd & 1;
    float mf = (cd & 0x100) ? 1.f : 0.f;
    float4 v = vcur;
    v.x *= mf; v.y *= mf; v.z *= mf; v.w *= mf;
    if (issep) {
      if (curseg != r) {
        flush_seg(sums, b, curseg, tid, acc);
        acc = make_float4(0.f, 0.f, 0.f, 0.f);
      }
      acc.x += v.x; acc.y += v.y; acc.z += v.z; acc.w += v.w;
      flush_seg(sums, b, r, tid, acc);
      if (r + 1 < SS) { curseg = r + 1; acc = v; }
      else { curseg = -1; acc = make_float4(0.f, 0.f, 0.f, 0.f); }
    } else {
      int sg = (r < SS) ? r : -1;
      if (sg != curseg) {
        flush_seg(sums, b, curseg, tid, acc);
        curseg = sg;
        acc = make_float4(0.f, 0.f, 0.f, 0.f);
      }
      acc.x += v.x; acc.y += v.y; acc.z += v.z; acc.w += v.w;
    }
    vcur = vnext;
  }
  flush_seg(sums, b, curseg, tid, acc);
}

// ---------------------------------------------------------------------------
// Kernel 3: split-K GEMM on raw sums (row scaling deferred to final).
// 64x64 tile, 4x4 microtile, k-major LDS, b128 reads. Partials, no atomics.
// ---------------------------------------------------------------------------
__global__ __launch_bounds__(256) void gemm1_kernel(
    const float* __restrict__ sums, const float* __restrict__ W1,
    float* __restrict__ h1p) {
  __shared__ float As[32][68];
  __shared__ float Bs[32][68];
  int bj = blockIdx.x;  // 0..15 col tile
  int bi = blockIdx.y;  // 0..3  row tile
  int bz = blockIdx.z;  // 0..7  K slice
  int tid = threadIdx.x;
  int r0 = bi * 64, c0 = bj * 64, kb = bz * KSLICE;

  int ai = tid >> 3;
  int af = tid & 7;
  int bk = tid >> 4;
  int bj4 = tid & 15;
  int tx = tid & 15, ty = tid >> 4;

  float acc[4][4];
#pragma unroll
  for (int i = 0; i < 4; i++)
#pragma unroll
    for (int j = 0; j < 4; j++) acc[i][j] = 0.f;

  for (int k0 = kb; k0 < kb + KSLICE; k0 += 32) {
    if (k0 != kb) __syncthreads();
    float4 a0 = *(const float4*)&sums[(size_t)(r0 + ai) * HH + k0 + af * 4];
    float4 a1 = *(const float4*)&sums[(size_t)(r0 + ai + 32) * HH + k0 + af * 4];
    float4 b0 = *(const float4*)&W1[(size_t)(k0 + bk) * HH + c0 + bj4 * 4];
    float4 b1 = *(const float4*)&W1[(size_t)(k0 + bk + 16) * HH + c0 + bj4 * 4];
    As[af * 4 + 0][ai] = a0.x;
    As[af * 4 + 1][ai] = a0.y;
    As[af * 4 + 2][ai] = a0.z;
    As[af * 4 + 3][ai] = a0.w;
    As[af * 4 + 0][ai + 32] = a1.x;
    As[af * 4 + 1][ai + 32] = a1.y;
    As[af * 4 + 2][ai + 32] = a1.z;
    As[af * 4 + 3][ai + 32] = a1.w;
    *(float4*)&Bs[bk][bj4 * 4] = b0;
    *(float4*)&Bs[bk + 16][bj4 * 4] = b1;
    __syncthreads();
#pragma unroll
    for (int kk = 0; kk < 32; kk++) {
      float4 a = *(const float4*)&As[kk][ty * 4];
      float4 b = *(const float4*)&Bs[kk][tx * 4];
      acc[0][0] += a.x * b.x; acc[0][1] += a.x * b.y;
      acc[0][2] += a.x * b.z; acc[0][3] += a.x * b.w;
      acc[1][0] += a.y * b.x; acc[1][1] += a.y * b.y;
      acc[1][2] += a.y * b.z; acc[1][3] += a.y * b.w;
      acc[2][0] += a.z * b.x; acc[2][1] += a.z * b.y;
      acc[2][2] += a.z * b.z; acc[2][3] += a.z * b.w;
      acc[3][0] += a.w * b.x; acc[3][1] += a.w * b.y;
      acc[3][2] += a.w * b.z; acc[3][3] += a.w * b.w;
    }
  }
#pragma unroll
  for (int dr = 0; dr < 4; dr++) {
    float4 o = make_float4(acc[dr][0], acc[dr][1], acc[dr][2], acc[dr][3]);
    *(float4*)&h1p[((size_t)bz * NROWS + r0 + ty * 4 + dr) * HH + c0 + tx * 4] = o;
  }
}

// ---------------------------------------------------------------------------
// Kernel 4: sum 8 partials, scale by 1/cnt, + b1 -> LN -> GELU -> @W2 + b2.
// ---------------------------------------------------------------------------
__global__ __launch_bounds__(256) void final_kernel(
    const float* __restrict__ h1p, const float* __restrict__ cnts,
    const float* __restrict__ b1, const float* __restrict__ ln_g,
    const float* __restrict__ ln_b, const float* __restrict__ W2,
    const float* __restrict__ b2, float* __restrict__ out) {
  int r = blockIdx.x;
  int tid = threadIdx.x;
  float4 x = make_float4(0.f, 0.f, 0.f, 0.f);
#pragma unroll
  for (int sl = 0; sl < SPLITK; sl++) {
    float4 p = ((const float4*)(h1p + ((size_t)sl * NROWS + r) * HH))[tid];
    x.x += p.x; x.y += p.y; x.z += p.z; x.w += p.w;
  }
  float invr = 1.0f / cnts[r];
  float4 bb1 = ((const float4*)b1)[tid];
  x.x = x.x * invr + bb1.x;
  x.y = x.y * invr + bb1.y;
  x.z = x.z * invr + bb1.z;
  x.w = x.w * invr + bb1.w;
  float s = x.x + x.y + x.z + x.w;
  float sq = x.x * x.x + x.y * x.y + x.z * x.z + x.w * x.w;
  __shared__ float redA[4], redB[4];
#pragma unroll
  for (int off = 32; off >= 1; off >>= 1) {
    s += __shfl_down(s, off, 64);
    sq += __shfl_down(sq, off, 64);
  }
  int wave = tid >> 6, lane = tid & 63;
  if (lane == 0) { redA[wave] = s; redB[wave] = sq; }
  __syncthreads();
  float ts = redA[0] + redA[1] + redA[2] + redA[3];
  float tq = redB[0] + redB[1] + redB[2] + redB[3];
  float mean = ts * (1.0f / HH);
  float var = tq * (1.0f / HH) - mean * mean;
  float rinv = rsqrtf(var + 1e-5f);
  float4 g4 = ((const float4*)ln_g)[tid];
  float4 bb4 = ((const float4*)ln_b)[tid];
  float4 w20 = ((const float4*)W2)[tid * 2];
  float4 w21 = ((const float4*)W2)[tid * 2 + 1];
  float xs[4] = {x.x, x.y, x.z, x.w};
  float gs[4] = {g4.x, g4.y, g4.z, g4.w};
  float bs[4] = {bb4.x, bb4.y, bb4.z, bb4.w};
  float w0[4] = {w20.x, w20.z, w21.x, w21.z};
  float w1[4] = {w20.y, w20.w, w21.y, w21.w};
  float o0 = 0.f, o1 = 0.f;
#pragma unroll
  for (int j = 0; j < 4; j++) {
    float y = (xs[j] - mean) * rinv * gs[j] + bs[j];
    float gel = 0.5f * y * (1.0f + erff(y * 0.70710678118654752440f));
    o0 += gel * w0[j];
    o1 += gel * w1[j];
  }
#pragma unroll
  for (int off = 32; off >= 1; off >>= 1) {
    o0 += __shfl_down(o0, off, 64);
    o1 += __shfl_down(o1, off, 64);
  }
  __syncthreads();
  if (lane == 0) { redA[wave] = o0; redB[wave] = o1; }
  __syncthreads();
  if (tid == 0) {
    out[(size_t)r * 2 + 0] = redA[0] + redA[1] + redA[2] + redA[3] + b2[0];
    out[(size_t)r * 2 + 1] = redB[0] + redB[1] + redB[2] + redB[3] + b2[1];
  }
}

// ---------------------------------------------------------------------------
extern "C" void kernel_launch(void* const* d_in, const int* in_sizes, int n_in,
                              void* d_out, int out_size, void* d_ws, size_t ws_size,
                              hipStream_t stream) {
  (void)in_sizes; (void)n_in; (void)out_size; (void)ws_size;
  const float* seq  = (const float*)d_in[0];
  const int*   ids  = (const int*)d_in[1];
  const int*   mask = (const int*)d_in[2];
  const float* W1   = (const float*)d_in[3];
  const float* b1   = (const float*)d_in[4];
  const float* ln_g = (const float*)d_in[5];
  const float* ln_b = (const float*)d_in[6];
  const float* W2   = (const float*)d_in[7];
  const float* b2   = (const float*)d_in[8];
  float* out = (float*)d_out;

  char* ws = (char*)d_ws;
  float* sums = (float*)ws;                         // 1 MB (zeroed by prep)
  float* h1p  = (float*)(ws + (1 << 20));           // 8 MB partials
  float* cnts = (float*)(ws + (9 << 20));           // 1 KB
  int*   spos = (int*)(ws + (9 << 20) + 4096);      // 1 KB

  dim3 gp(BB, 9);
  prep_kernel<<<gp, 256, 0, stream>>>(ids, mask, cnts, spos, sums);
  segsum_kernel<<<BB * (LL / TOK), 256, 0, stream>>>(
      (const float4*)seq, mask, spos, sums);
  dim3 g1(16, 4, SPLITK);
  gemm1_kernel<<<g1, 256, 0, stream>>>(sums, W1, h1p);
  final_kernel<<<NROWS, 256, 0, stream>>>(h1p, cnts, b1, ln_g, ln_b, W2, b2, out);
}

// Round 5
// 233.608 us; speedup vs baseline: 1.2037x; 1.0269x over previous
//
#include <hip/hip_runtime.h>
#include <math.h>

#define BB 8
#define LL 4096
#define HH 1024
#define SS 32
#define SEPID 102
#define NROWS 256   // B*S
#define TOK 64
#define SPLITK 8
#define KSLICE (HH / SPLITK)  // 128

// ---------------------------------------------------------------------------
// Kernel 1: per-batch prep + sums zeroing.
// blockIdx.y == 0: find SEP positions (sorted) -> spos_g, masked counts via
// block scan -> cnts. blockIdx.y in 1..8: zero a slice of sums.
// ---------------------------------------------------------------------------
__global__ __launch_bounds__(256) void prep_kernel(
    const int* __restrict__ ids, const int* __restrict__ mask,
    float* __restrict__ cnts, int* __restrict__ spos_g,
    float* __restrict__ sums) {
  int b = blockIdx.x;
  int by = blockIdx.y;
  int tid = threadIdx.x;
  if (by > 0) {
    int z = b * 8 + (by - 1);
    float4 zero = make_float4(0.f, 0.f, 0.f, 0.f);
    float4* p = (float4*)sums + (size_t)z * 1024;
#pragma unroll
    for (int i = 0; i < 4; i++) p[tid + i * 256] = zero;
    return;
  }
  __shared__ int spos_raw[SS];
  __shared__ int spos[SS];
  __shared__ int nsep;
  __shared__ int excl_s[257];
  __shared__ int wtot[4];
  if (tid == 0) nsep = 0;
  if (tid < SS) spos_raw[tid] = LL - 1;
  __syncthreads();
  const int* idb = ids + (size_t)b * LL;
  const int* mb  = mask + (size_t)b * LL;

  for (int t = tid; t < LL; t += 256) {
    if (idb[t] == SEPID) {
      int slot = atomicAdd(&nsep, 1);
      if (slot < SS) spos_raw[slot] = t;
    }
  }
  __syncthreads();
  if (tid < SS) {
    int p = spos_raw[tid];
    int rank = 0;
    for (int j = 0; j < SS; j++) {
      int q = spos_raw[j];
      rank += (q < p) || (q == p && j < tid);
    }
    spos[rank] = p;
  }

  int local = 0;
  int base = tid * 16;
#pragma unroll
  for (int i = 0; i < 16; i++) local += mb[base + i];
  int lane = tid & 63, wave = tid >> 6;
  int v = local;
#pragma unroll
  for (int off = 1; off < 64; off <<= 1) {
    int n = __shfl_up(v, off, 64);
    if (lane >= off) v += n;
  }
  if (lane == 63) wtot[wave] = v;
  __syncthreads();
  int woff = 0;
  for (int w = 0; w < wave; w++) woff += wtot[w];
  excl_s[tid] = woff + v - local;
  if (tid == 0) excl_s[256] = wtot[0] + wtot[1] + wtot[2] + wtot[3];
  __syncthreads();

  if (tid < SS) {
    spos_g[b * SS + tid] = spos[tid];
    int st = (tid == 0) ? 0 : spos[tid - 1];
    int ed = spos[tid];
    int pa = st, pb = ed + 1;
    int ca = excl_s[pa >> 4];
    for (int i = pa & ~15; i < pa; i++) ca += mb[i];
    int cb = excl_s[pb >> 4];
    for (int i = pb & ~15; i < pb; i++) cb += mb[i];
    cnts[b * SS + tid] = (float)max(cb - ca, 1);
  }
}

// ---------------------------------------------------------------------------
// Kernel 2: segment sums. Block = 64-token chunk; codes from binary search of
// the 32 sorted SEP positions. Group-of-4 double-buffered register prefetch:
// 4 outstanding 16B loads/thread (32 KB/CU in flight > 9.2 KB MLP requirement
// at 900-cyc HBM latency), so the serial flush logic never starves the bus.
// ---------------------------------------------------------------------------
__device__ __forceinline__ void flush_seg(float* __restrict__ sums, int b,
                                          int seg, int tid, const float4& acc) {
  if (seg >= 0) {
    float* p = sums + ((size_t)(b * SS + seg)) * HH + tid * 4;
    atomicAdd(p + 0, acc.x);
    atomicAdd(p + 1, acc.y);
    atomicAdd(p + 2, acc.z);
    atomicAdd(p + 3, acc.w);
  }
}

__global__ __launch_bounds__(256) void segsum_kernel(
    const float4* __restrict__ seq, const int* __restrict__ mask,
    const int* __restrict__ spos_g, float* __restrict__ sums) {
  const int chunks = LL / TOK;  // 64
  int b = blockIdx.x / chunks;
  int c = blockIdx.x % chunks;
  int t0 = c * TOK;
  int tid = threadIdx.x;
  __shared__ int sposs[SS];
  __shared__ int scode[TOK];
  if (tid < SS) sposs[tid] = spos_g[b * SS + tid];
  __syncthreads();
  if (t0 > sposs[SS - 1]) return;  // whole chunk after last SEP
  if (tid < TOK) {
    int t = t0 + tid;
    int lo = 0, hi = SS;
    while (lo < hi) {
      int mid = (lo + hi) >> 1;
      if (sposs[mid] < t) lo = mid + 1; else hi = mid;
    }
    int issep = (lo < SS && sposs[lo] == t) ? 1 : 0;
    int r = lo;
    int m = mask[(size_t)b * LL + t];
    int live = (issep || r < SS) ? 1 : 0;
    scode[tid] = ((r << 1) | issep) | ((m && live) ? 0x100 : 0);
  }
  __syncthreads();
  float4 acc = make_float4(0.f, 0.f, 0.f, 0.f);
  int curseg = -1;
  const int rs = HH / 4;
  const float4* rowbase = seq + (size_t)(b * LL + t0) * rs + tid;
  float4 cur[4], nxt[4];
#pragma unroll
  for (int j = 0; j < 4; j++) cur[j] = rowbase[(size_t)j * rs];
  for (int g = 0; g < TOK / 4; g++) {
    int tb = g * 4;
    if (g < TOK / 4 - 1) {
#pragma unroll
      for (int j = 0; j < 4; j++) nxt[j] = rowbase[(size_t)(tb + 4 + j) * rs];
    }
#pragma unroll
    for (int j = 0; j < 4; j++) {
      int cd = scode[tb + j];
      int r = (cd >> 1) & 0x3F;
      int issep = cd & 1;
      float mf = (cd & 0x100) ? 1.f : 0.f;
      float4 v = cur[j];
      v.x *= mf; v.y *= mf; v.z *= mf; v.w *= mf;
      if (issep) {
        if (curseg != r) {
          flush_seg(sums, b, curseg, tid, acc);
          acc = make_float4(0.f, 0.f, 0.f, 0.f);
        }
        acc.x += v.x; acc.y += v.y; acc.z += v.z; acc.w += v.w;
        flush_seg(sums, b, r, tid, acc);
        if (r + 1 < SS) { curseg = r + 1; acc = v; }
        else { curseg = -1; acc = make_float4(0.f, 0.f, 0.f, 0.f); }
      } else {
        int sg = (r < SS) ? r : -1;
        if (sg != curseg) {
          flush_seg(sums, b, curseg, tid, acc);
          curseg = sg;
          acc = make_float4(0.f, 0.f, 0.f, 0.f);
        }
        acc.x += v.x; acc.y += v.y; acc.z += v.z; acc.w += v.w;
      }
    }
#pragma unroll
    for (int j = 0; j < 4; j++) cur[j] = nxt[j];
  }
  flush_seg(sums, b, curseg, tid, acc);
}

// ---------------------------------------------------------------------------
// Kernel 3: split-K GEMM on raw sums (row scaling deferred to final).
// 64x64 tile, 4x4 microtile, k-major LDS, b128 reads. Partials, no atomics.
// ---------------------------------------------------------------------------
__global__ __launch_bounds__(256) void gemm1_kernel(
    const float* __restrict__ sums, const float* __restrict__ W1,
    float* __restrict__ h1p) {
  __shared__ float As[32][68];
  __shared__ float Bs[32][68];
  int bj = blockIdx.x;
  int bi = blockIdx.y;
  int bz = blockIdx.z;
  int tid = threadIdx.x;
  int r0 = bi * 64, c0 = bj * 64, kb = bz * KSLICE;

  int ai = tid >> 3;
  int af = tid & 7;
  int bk = tid >> 4;
  int bj4 = tid & 15;
  int tx = tid & 15, ty = tid >> 4;

  float acc[4][4];
#pragma unroll
  for (int i = 0; i < 4; i++)
#pragma unroll
    for (int j = 0; j < 4; j++) acc[i][j] = 0.f;

  for (int k0 = kb; k0 < kb + KSLICE; k0 += 32) {
    if (k0 != kb) __syncthreads();
    float4 a0 = *(const float4*)&sums[(size_t)(r0 + ai) * HH + k0 + af * 4];
    float4 a1 = *(const float4*)&sums[(size_t)(r0 + ai + 32) * HH + k0 + af * 4];
    float4 b0 = *(const float4*)&W1[(size_t)(k0 + bk) * HH + c0 + bj4 * 4];
    float4 b1 = *(const float4*)&W1[(size_t)(k0 + bk + 16) * HH + c0 + bj4 * 4];
    As[af * 4 + 0][ai] = a0.x;
    As[af * 4 + 1][ai] = a0.y;
    As[af * 4 + 2][ai] = a0.z;
    As[af * 4 + 3][ai] = a0.w;
    As[af * 4 + 0][ai + 32] = a1.x;
    As[af * 4 + 1][ai + 32] = a1.y;
    As[af * 4 + 2][ai + 32] = a1.z;
    As[af * 4 + 3][ai + 32] = a1.w;
    *(float4*)&Bs[bk][bj4 * 4] = b0;
    *(float4*)&Bs[bk + 16][bj4 * 4] = b1;
    __syncthreads();
#pragma unroll
    for (int kk = 0; kk < 32; kk++) {
      float4 a = *(const float4*)&As[kk][ty * 4];
      float4 b = *(const float4*)&Bs[kk][tx * 4];
      acc[0][0] += a.x * b.x; acc[0][1] += a.x * b.y;
      acc[0][2] += a.x * b.z; acc[0][3] += a.x * b.w;
      acc[1][0] += a.y * b.x; acc[1][1] += a.y * b.y;
      acc[1][2] += a.y * b.z; acc[1][3] += a.y * b.w;
      acc[2][0] += a.z * b.x; acc[2][1] += a.z * b.y;
      acc[2][2] += a.z * b.z; acc[2][3] += a.z * b.w;
      acc[3][0] += a.w * b.x; acc[3][1] += a.w * b.y;
      acc[3][2] += a.w * b.z; acc[3][3] += a.w * b.w;
    }
  }
#pragma unroll
  for (int dr = 0; dr < 4; dr++) {
    float4 o = make_float4(acc[dr][0], acc[dr][1], acc[dr][2], acc[dr][3]);
    *(float4*)&h1p[((size_t)bz * NROWS + r0 + ty * 4 + dr) * HH + c0 + tx * 4] = o;
  }
}

// ---------------------------------------------------------------------------
// Kernel 4: sum 8 partials, scale by 1/cnt, + b1 -> LN -> GELU -> @W2 + b2.
// ---------------------------------------------------------------------------
__global__ __launch_bounds__(256) void final_kernel(
    const float* __restrict__ h1p, const float* __restrict__ cnts,
    const float* __restrict__ b1, const float* __restrict__ ln_g,
    const float* __restrict__ ln_b, const float* __restrict__ W2,
    const float* __restrict__ b2, float* __restrict__ out) {
  int r = blockIdx.x;
  int tid = threadIdx.x;
  float4 x = make_float4(0.f, 0.f, 0.f, 0.f);
#pragma unroll
  for (int sl = 0; sl < SPLITK; sl++) {
    float4 p = ((const float4*)(h1p + ((size_t)sl * NROWS + r) * HH))[tid];
    x.x += p.x; x.y += p.y; x.z += p.z; x.w += p.w;
  }
  float invr = 1.0f / cnts[r];
  float4 bb1 = ((const float4*)b1)[tid];
  x.x = x.x * invr + bb1.x;
  x.y = x.y * invr + bb1.y;
  x.z = x.z * invr + bb1.z;
  x.w = x.w * invr + bb1.w;
  float s = x.x + x.y + x.z + x.w;
  float sq = x.x * x.x + x.y * x.y + x.z * x.z + x.w * x.w;
  __shared__ float redA[4], redB[4];
#pragma unroll
  for (int off = 32; off >= 1; off >>= 1) {
    s += __shfl_down(s, off, 64);
    sq += __shfl_down(sq, off, 64);
  }
  int wave = tid >> 6, lane = tid & 63;
  if (lane == 0) { redA[wave] = s; redB[wave] = sq; }
  __syncthreads();
  float ts = redA[0] + redA[1] + redA[2] + redA[3];
  float tq = redB[0] + redB[1] + redB[2] + redB[3];
  float mean = ts * (1.0f / HH);
  float var = tq * (1.0f / HH) - mean * mean;
  float rinv = rsqrtf(var + 1e-5f);
  float4 g4 = ((const float4*)ln_g)[tid];
  float4 bb4 = ((const float4*)ln_b)[tid];
  float4 w20 = ((const float4*)W2)[tid * 2];
  float4 w21 = ((const float4*)W2)[tid * 2 + 1];
  float xs[4] = {x.x, x.y, x.z, x.w};
  float gs[4] = {g4.x, g4.y, g4.z, g4.w};
  float bs[4] = {bb4.x, bb4.y, bb4.z, bb4.w};
  float w0[4] = {w20.x, w20.z, w21.x, w21.z};
  float w1[4] = {w20.y, w20.w, w21.y, w21.w};
  float o0 = 0.f, o1 = 0.f;
#pragma unroll
  for (int j = 0; j < 4; j++) {
    float y = (xs[j] - mean) * rinv * gs[j] + bs[j];
    float gel = 0.5f * y * (1.0f + erff(y * 0.70710678118654752440f));
    o0 += gel * w0[j];
    o1 += gel * w1[j];
  }
#pragma unroll
  for (int off = 32; off >= 1; off >>= 1) {
    o0 += __shfl_down(o0, off, 64);
    o1 += __shfl_down(o1, off, 64);
  }
  __syncthreads();
  if (lane == 0) { redA[wave] = o0; redB[wave] = o1; }
  __syncthreads();
  if (tid == 0) {
    out[(size_t)r * 2 + 0] = redA[0] + redA[1] + redA[2] + redA[3] + b2[0];
    out[(size_t)r * 2 + 1] = redB[0] + redB[1] + redB[2] + redB[3] + b2[1];
  }
}

// ---------------------------------------------------------------------------
extern "C" void kernel_launch(void* const* d_in, const int* in_sizes, int n_in,
                              void* d_out, int out_size, void* d_ws, size_t ws_size,
                              hipStream_t stream) {
  (void)in_sizes; (void)n_in; (void)out_size; (void)ws_size;
  const float* seq  = (const float*)d_in[0];
  const int*   ids  = (const int*)d_in[1];
  const int*   mask = (const int*)d_in[2];
  const float* W1   = (const float*)d_in[3];
  const float* b1   = (const float*)d_in[4];
  const float* ln_g = (const float*)d_in[5];
  const float* ln_b = (const float*)d_in[6];
  const float* W2   = (const float*)d_in[7];
  const float* b2   = (const float*)d_in[8];
  float* out = (float*)d_out;

  char* ws = (char*)d_ws;
  float* sums = (float*)ws;                         // 1 MB (zeroed by prep)
  float* h1p  = (float*)(ws + (1 << 20));           // 8 MB partials
  float* cnts = (float*)(ws + (9 << 20));           // 1 KB
  int*   spos = (int*)(ws + (9 << 20) + 4096);      // 1 KB

  dim3 gp(BB, 9);
  prep_kernel<<<gp, 256, 0, stream>>>(ids, mask, cnts, spos, sums);
  segsum_kernel<<<BB * (LL / TOK), 256, 0, stream>>>(
      (const float4*)seq, mask, spos, sums);
  dim3 g1(16, 4, SPLITK);
  gemm1_kernel<<<g1, 256, 0, stream>>>(sums, W1, h1p);
  final_kernel<<<NROWS, 256, 0, stream>>>(h1p, cnts, b1, ln_g, ln_b, W2, b2, out);
}